// Round 8
// baseline (159.316 us; speedup 1.0000x reference)
//
#include <hip/hip_runtime.h>
#include <math.h>

#define B_IMG 16
#define N_PROP 2048
#define C_CLS 3
#define K_OUT 100
#define NUNITS (B_IMG * N_PROP)           // 32768 (img,n) units

#define NTH2 256                          // nms kernel threads
#define NW2 (NTH2 / 64)
#define NBLK64 (N_PROP / 64)
#define SORTN 512                         // fast-path sort window
#define TSEL 256                          // top-T selection target

__device__ __forceinline__ unsigned long long shfl_xor_u64(unsigned long long v, int lx) {
    unsigned int lo = (unsigned int)__shfl_xor((int)(unsigned int)(v & 0xffffffffull), lx, 64);
    unsigned int hi = (unsigned int)__shfl_xor((int)(unsigned int)(v >> 32), lx, 64);
    return ((unsigned long long)hi << 32) | (unsigned long long)lo;
}
__device__ __forceinline__ float readlane_f(float v, int l) {
    return __int_as_float(__builtin_amdgcn_readlane(__float_as_int(v), l));
}
__device__ __forceinline__ unsigned int readlane_u32(unsigned int v, int l) {
    return (unsigned int)__builtin_amdgcn_readlane((int)v, l);
}
// Exact replacement for: RN(inter / max(uni,1e-8f)) > 0.5f
// RN(a/b) > 0.5 <=> a/b > 0.5+2^-25 <=> 2a > b*(1+2^-24); b*(1+2^-24) exact in
// double (24+25=49 < 53 bits). Bit-equivalent to the reference decision.
__device__ __forceinline__ bool iou_gt_half(float inter, float uni) {
    double b = (double)fmaxf(uni, 1e-8f);
    return (double)inter * 2.0 > b * 0x1.000001p0;
}
__device__ __forceinline__ float parse_imgf(int raw) {
    return (raw > 0 && raw < 1000000) ? (float)raw : __int_as_float(raw);
}

// ---------------- kernel 1: decode on the full chip ----------------
__global__ __launch_bounds__(256)
void decode_kernel(const float* __restrict__ class_logit,
                   const float* __restrict__ box_reg,
                   const float* __restrict__ proposal,
                   const int* __restrict__ image_shape_p,
                   unsigned long long* __restrict__ wskey,   // [2][NUNITS]
                   float2* __restrict__ wbox)                // [2][NUNITS]
{
#pragma clang fp contract(off)
    const int t = blockIdx.x * 256 + threadIdx.x;   // 0..NUNITS-1
    const int n = t & (N_PROP - 1);
    const float imgf = parse_imgf(image_shape_p[0]);

    const float* lg = class_logit + (size_t)t * C_CLS;
    float l0 = lg[0], l1 = lg[1], l2 = lg[2];
    float mx = fmaxf(l0, fmaxf(l1, l2));
    float e0 = (float)exp((double)(l0 - mx));
    float e1 = (float)exp((double)(l1 - mx));
    float e2 = (float)exp((double)(l2 - mx));
    float denom = (e0 + e1) + e2;

    const float* pp = proposal + (size_t)t * 2;
    float pA = pp[0], pB = pp[1];
    float w = pB - pA;
    float ctr = pA + 0.5f * w;

    const float* dr = box_reg + (size_t)t * (2 * C_CLS);
    float d1x = dr[2], d1w = dr[3], d2x = dr[4], d2w = dr[5];

#pragma unroll
    for (int c = 0; c < 2; ++c) {
        float score = ((c == 0) ? e1 : e2) / denom;
        float dx = (c == 0) ? d1x : d2x;                 // / WX == 1
        float dw = fminf((c == 0) ? d1w : d2w, 4.0f);    // / WW == 1, clamp 4
        float tt = dx * w;
        float pc = tt + ctr;
        float pw = (float)exp((double)dw) * w;
        float half = 0.5f * pw;
        float lo = pc - half;
        float hi = pc + half;
        lo = fminf(fmaxf(lo, 0.0f), imgf);
        hi = fminf(fmaxf(hi, 0.0f), imgf);
        bool valid = ((hi - lo) >= 10.0f) && (score >= 0.05f);
        float ms = valid ? score : -1e9f;
        unsigned int u = __float_as_uint(ms);
        unsigned int e = (u & 0x80000000u) ? ~u : (u | 0x80000000u);  // order-preserving
        wskey[c * NUNITS + t] = ((unsigned long long)e << 32) |
                                (unsigned long long)(0xFFFFFFFFu - (unsigned int)n);
        wbox[c * NUNITS + t] = make_float2(lo, hi);
    }
}

// ---------------- kernel 2: top-M select + sort + NMS + emit ----------------
// Greedy-NMS keep decisions for the first P sorted positions depend only on
// the first P positions; once 100 are kept, later decisions are unused.
// Top-M selection by key-high-bits bin threshold yields EXACTLY the first M
// entries of the full sorted order (bin is a prefix of the key). Fallback to
// the full 2048 path if the window can't certify 100 kept.
__global__ __launch_bounds__(NTH2)
void nms_kernel(const unsigned long long* __restrict__ wskey,
                const float2* __restrict__ wbox,
                float* __restrict__ out)
{
#pragma clang fp contract(off)
    __shared__ unsigned long long skey[N_PROP];     // 16 KB
    __shared__ float slo[N_PROP], shi[N_PROP];      // 16 KB
    __shared__ unsigned char keep[N_PROP];
    __shared__ unsigned short alv[2][N_PROP];       // 8 KB
    __shared__ unsigned int hist[4096];             // 16 KB
    __shared__ float clo[64], chi[64];
    __shared__ unsigned long long kmask[NBLK64];
    __shared__ int wsum[NW2];
    __shared__ int sh_cnt, sh_nv, sh_ccnt, sh_thr, sh_M;

    const int tid = threadIdx.x;
    const int lane = tid & 63;
    const int wid = tid >> 6;
    const int img = blockIdx.x >> 1;
    const int cls = blockIdx.x & 1;
    const size_t base = (size_t)cls * NUNITS + (size_t)img * N_PROP;
    const unsigned long long below = (1ull << lane) - 1ull;

    // ---- init + histogram of key high-12-bits ----
    for (int i = tid; i < 4096; i += NTH2) hist[i] = 0;
    if (tid == 0) { sh_cnt = 0; }
    __syncthreads();

    unsigned long long k8[8];
#pragma unroll
    for (int u = 0; u < 8; ++u) {
        unsigned long long k = wskey[base + u * NTH2 + tid];   // coalesced
        k8[u] = k;
        atomicAdd(&hist[(unsigned int)(k >> 52)], 1u);
    }
    __syncthreads();

    // ---- wave 0: threshold bin b* = max b with F(b)=count(bin>=b) >= TSEL ----
    if (wid == 0) {
        unsigned int csum = 0;
        int b0 = lane * 64;
        for (int i = 0; i < 64; ++i) csum += hist[b0 + i];
        unsigned int S = csum;                        // suffix over lanes
        for (int d = 1; d < 64; d <<= 1) {
            unsigned int t2 = __shfl_down(S, d, 64);
            if (lane + d < 64) S += t2;
        }
        unsigned long long bm = __ballot(S >= (unsigned)TSEL);  // lane0 always set
        int lstar = 63 - __clzll((long long)bm);
        unsigned int Snext = 0;
        if (lstar < 63) Snext = readlane_u32(S, lstar + 1);
        if (lane == 0) {
            unsigned int G = Snext;
            int b = lstar * 64 + 63;
            for (; b >= lstar * 64; --b) {
                G += hist[b];
                if (G >= (unsigned)TSEL) break;
            }
            sh_thr = b; sh_M = (int)G;
        }
    }
    __syncthreads();
    const unsigned int thr = (unsigned int)sh_thr;
    const int M = sh_M;

    // ---------------- generic NMS + emission helpers ----------------
    auto run_nms = [&](int total) -> int {
#pragma clang fp contract(off)
        int na = sh_nv;
        int cur = 0, tk = 0;
        while (na > 0) {
            const int m = (na < 64) ? na : 64;
            if (tid < 64) {
                bool inr = (lane < m);
                unsigned short p = inr ? alv[cur][lane] : (unsigned short)0;
                float blo = inr ? slo[p] : 0.0f;
                float bhi = inr ? shi[p] : 0.0f;
                float bw = bhi - blo;
                unsigned long long A = (m >= 64) ? ~0ull : ((1ull << m) - 1ull);
                unsigned long long kept = 0;
                while (A) {
                    int c = __builtin_ctzll(A);
                    float cl = readlane_f(blo, c);
                    float ch = readlane_f(bhi, c);
                    float inter = fmaxf(fminf(bhi, ch) - fmaxf(blo, cl), 0.0f);
                    float uni = bw + (ch - cl) - inter;
                    bool kill = (lane > c) && iou_gt_half(inter, uni);
                    unsigned long long row = __ballot(kill);
                    kept |= (1ull << c);
                    A &= ~(row | (1ull << c));
                }
                bool alive = inr && ((kept >> lane) & 1ull);
                if (alive) keep[p] = 1;
                int rank = __popcll(kept & below);
                if (alive) { clo[rank] = blo; chi[rank] = bhi; }
                if (lane == 0) sh_ccnt = __popcll(kept);
            }
            __syncthreads();
            const int cnt = sh_ccnt;
            tk += cnt;
            if (tk >= K_OUT) break;   // later decisions provably unused

            float klo = 0.0f, khi = 0.0f;
            if (lane < cnt) { klo = clo[lane]; khi = chi[lane]; }
            int base2 = 0;
            for (int start = 64; start < na; start += NTH2) {
                int t2 = start + tid;
                unsigned short q = 0;
                bool surv = false;
                if (t2 < na) {
                    q = alv[cur][t2];
                    float qlo = slo[q], qhi = shi[q];
                    float qw = qhi - qlo;
                    bool dead = false;
                    for (int r = 0; r < cnt; ++r) {
                        float cl = readlane_f(klo, r);
                        float ch = readlane_f(khi, r);
                        float inter = fmaxf(fminf(qhi, ch) - fmaxf(qlo, cl), 0.0f);
                        float uni = qw + (ch - cl) - inter;
                        dead |= iou_gt_half(inter, uni);
                    }
                    surv = !dead;
                }
                unsigned long long mb = __ballot(surv);
                if (lane == 0) wsum[wid] = __popcll(mb);
                __syncthreads();
                int off = base2, tot = base2;
                for (int w2 = 0; w2 < NW2; ++w2) {
                    int c2 = wsum[w2];
                    if (w2 < wid) off += c2;
                    tot += c2;
                }
                if (surv) alv[cur ^ 1][off + __popcll(mb & below)] = q;
                base2 = tot;
                __syncthreads();
            }
            na = base2;
            cur ^= 1;
        }
        return tk;
    };

    auto emit = [&](int nblk) {
        for (int blk = wid; blk < nblk; blk += NW2) {
            bool kk = keep[blk * 64 + lane] != 0;
            unsigned long long mb = __ballot(kk);
            if (lane == 0) kmask[blk] = mb;
        }
        __syncthreads();
        float* outp = out + (((size_t)img * 2 + cls) * K_OUT) * 3;
        for (int blk = wid; blk < nblk; blk += NW2) {
            int kc = 0, nc = 0, nk = 0;
            for (int b = 0; b < nblk; ++b) {
                int pc = __popcll(kmask[b]);
                nk += pc;
                if (b < blk) { kc += pc; nc += 64 - pc; }
            }
            int p = blk * 64 + lane;
            unsigned long long mb = kmask[blk];
            bool k = (mb >> lane) & 1ull;
            int rk = kc + __popcll(mb & below);
            int rn = nc + __popcll((~mb) & below);
            if (k) {
                if (rk < K_OUT) {
                    unsigned long long kk2 = skey[p];
                    unsigned int e = (unsigned int)(kk2 >> 32);
                    unsigned int sb = (e & 0x80000000u) ? (e & 0x7FFFFFFFu) : ~e;
                    outp[rk * 3 + 0] = slo[p];
                    outp[rk * 3 + 1] = shi[p];
                    outp[rk * 3 + 2] = __uint_as_float(sb);
                }
            } else {
                int oi = nk + rn;   // nk >= K on fast path -> never fires there
                if (oi < K_OUT) {
                    outp[oi * 3 + 0] = slo[p];
                    outp[oi * 3 + 1] = shi[p];
                    outp[oi * 3 + 2] = -1e9f;
                }
            }
        }
    };

    // ---------------- fast path: top-M window ----------------
    bool done = false;
    if (M <= SORTN) {
        // compact selected keys into skey[0..M) (order irrelevant: full sort next)
        int myc = 0;
#pragma unroll
        for (int u = 0; u < 8; ++u) myc += ((unsigned int)(k8[u] >> 52) >= thr);
        int off = atomicAdd(&sh_cnt, myc);
#pragma unroll
        for (int u = 0; u < 8; ++u)
            if ((unsigned int)(k8[u] >> 52) >= thr) skey[off++] = k8[u];
        for (int i = M + tid; i < SORTN; i += NTH2) skey[i] = 0ull;  // pad sinks
        __syncthreads();

        // sort SORTN descending: 2 keys/thread, reg bitonic j<=64 + LDS j>=128
        const int p0 = (wid << 7) | (lane << 1);
        const int p1 = p0 | 1;
        unsigned long long r0 = skey[p0], r1 = skey[p1];
        auto pass_inreg = [&](int k, int j) {
            if (j == 1) {
                bool desc = ((p0 & k) == 0);
                bool sw = desc ? (r0 < r1) : (r0 > r1);
                if (sw) { unsigned long long t2 = r0; r0 = r1; r1 = t2; }
            } else {
                int lx = j >> 1;
                unsigned long long o0 = shfl_xor_u64(r0, lx);
                unsigned long long o1 = shfl_xor_u64(r1, lx);
                bool desc = ((p0 & k) == 0);
                bool lower = ((p0 & j) == 0);
                bool takeMax = (lower == desc);
                r0 = takeMax ? (r0 > o0 ? r0 : o0) : (r0 < o0 ? r0 : o0);
                r1 = takeMax ? (r1 > o1 ? r1 : o1) : (r1 < o1 ? r1 : o1);
            }
        };
        for (int k = 2; k <= 128; k <<= 1)
            for (int j = k >> 1; j >= 1; j >>= 1)
                pass_inreg(k, j);
        for (int k = 256; k <= SORTN; k <<= 1) {
            skey[p0] = r0; skey[p1] = r1;
            __syncthreads();
            for (int j = k >> 1; j >= 128; j >>= 1) {
                int i = ((tid & ~(j - 1)) << 1) | (tid & (j - 1));
                int part = i | j;
                unsigned long long a = skey[i], b = skey[part];
                bool desc_blk = ((i & k) == 0);
                bool sw = desc_blk ? (a < b) : (a > b);
                if (sw) { skey[i] = b; skey[part] = a; }
                __syncthreads();
            }
            r0 = skey[p0]; r1 = skey[p1];
            for (int j = 64; j >= 1; j >>= 1)
                pass_inreg(k, j);
        }
        skey[p0] = r0; skey[p1] = r1;
        if (tid == 0) sh_nv = 0;
        __syncthreads();

        // gather boxes for window, init keep + alive list
        for (int i = tid; i < SORTN; i += NTH2) {
            unsigned long long kk = skey[i];
            unsigned int e = (unsigned int)(kk >> 32);
            unsigned int sb = (e & 0x80000000u) ? (e & 0x7FFFFFFFu) : ~e;
            float s = __uint_as_float(sb);
            bool inw = (i < M);
            if (inw) {
                unsigned int n = 0xFFFFFFFFu - (unsigned int)(kk & 0xFFFFFFFFull);
                float2 bx = wbox[base + n];
                slo[i] = bx.x; shi[i] = bx.y;
            } else { slo[i] = 0.0f; shi[i] = 0.0f; }
            keep[i] = 0;
            bool v = inw && (s > -5e8f);
            unsigned long long mb = __ballot(v);
            if (lane == 0) atomicAdd(&sh_nv, __popcll(mb));
            alv[0][i] = (unsigned short)i;
        }
        __syncthreads();

        int tk = run_nms(SORTN);
        if (tk >= K_OUT) { emit(SORTN / 64); done = true; }
    }

    // ---------------- fallback: full 2048 path (rarely/never taken) ----------------
    if (!done) {
        __syncthreads();
        for (int i = tid; i < N_PROP; i += NTH2) skey[i] = wskey[base + i];
        if (tid == 0) sh_nv = 0;
        __syncthreads();
        // plain LDS bitonic, descending
        for (int k = 2; k <= N_PROP; k <<= 1) {
            for (int j = k >> 1; j >= 1; j >>= 1) {
                for (int s = tid; s < N_PROP / 2; s += NTH2) {
                    int i = ((s & ~(j - 1)) << 1) | (s & (j - 1));
                    int part = i | j;
                    unsigned long long a = skey[i], b = skey[part];
                    bool desc_blk = ((i & k) == 0);
                    bool sw = desc_blk ? (a < b) : (a > b);
                    if (sw) { skey[i] = b; skey[part] = a; }
                }
                __syncthreads();
            }
        }
        for (int i = tid; i < N_PROP; i += NTH2) {
            unsigned long long kk = skey[i];
            unsigned int e = (unsigned int)(kk >> 32);
            unsigned int sb = (e & 0x80000000u) ? (e & 0x7FFFFFFFu) : ~e;
            float s = __uint_as_float(sb);
            unsigned int n = 0xFFFFFFFFu - (unsigned int)(kk & 0xFFFFFFFFull);
            float2 bx = wbox[base + n];
            slo[i] = bx.x; shi[i] = bx.y;
            keep[i] = 0;
            bool v = (s > -5e8f);
            unsigned long long mb = __ballot(v);
            if (lane == 0) atomicAdd(&sh_nv, __popcll(mb));
            alv[0][i] = (unsigned short)i;
        }
        __syncthreads();
        (void)run_nms(N_PROP);
        emit(NBLK64);
    }
}

extern "C" void kernel_launch(void* const* d_in, const int* in_sizes, int n_in,
                              void* d_out, int out_size, void* d_ws, size_t ws_size,
                              hipStream_t stream) {
    const float* class_logit = (const float*)d_in[0];
    const float* box_reg     = (const float*)d_in[1];
    const float* prop        = (const float*)d_in[2];
    const int*   image_shape = (const int*)d_in[3];
    float* out = (float*)d_out;

    unsigned long long* wskey = (unsigned long long*)d_ws;            // 512 KB
    float2* wbox = (float2*)((char*)d_ws + 2 * NUNITS * sizeof(unsigned long long));

    decode_kernel<<<dim3(NUNITS / 256), dim3(256), 0, stream>>>(
        class_logit, box_reg, prop, image_shape, wskey, wbox);
    nms_kernel<<<dim3(B_IMG * 2), dim3(NTH2), 0, stream>>>(wskey, wbox, out);
}

// Round 9
// 97.942 us; speedup vs baseline: 1.6266x; 1.6266x over previous
//
#include <hip/hip_runtime.h>
#include <math.h>

#define B_IMG 16
#define N_PROP 2048
#define C_CLS 3
#define K_OUT 100
#define NTHREADS 1024
#define NWAVES (NTHREADS / 64)
#define NBLK64 (N_PROP / 64)
#define NUNITS (B_IMG * N_PROP)           // 32768 (img,n) units

__device__ __forceinline__ unsigned long long shfl_xor_u64(unsigned long long v, int lx) {
    unsigned int lo = (unsigned int)__shfl_xor((int)(unsigned int)(v & 0xffffffffull), lx, 64);
    unsigned int hi = (unsigned int)__shfl_xor((int)(unsigned int)(v >> 32), lx, 64);
    return ((unsigned long long)hi << 32) | (unsigned long long)lo;
}
__device__ __forceinline__ float readlane_f(float v, int l) {
    return __int_as_float(__builtin_amdgcn_readlane(__float_as_int(v), l));
}
__device__ __forceinline__ unsigned long long readlane_u64(unsigned long long v, int l) {
    unsigned int lo = (unsigned int)__builtin_amdgcn_readlane((int)(unsigned int)(v & 0xffffffffull), l);
    unsigned int hi = (unsigned int)__builtin_amdgcn_readlane((int)(unsigned int)(v >> 32), l);
    return ((unsigned long long)hi << 32) | (unsigned long long)lo;
}
// Exact replacement for: RN(inter / max(uni,1e-8f)) > 0.5f
// RN(a/b) > 0.5 <=> a/b > 0.5+2^-25 <=> 2a > b*(1+2^-24); b*(1+2^-24) exact in
// double (24+25=49 < 53 bits). Bit-equivalent to the reference decision.
__device__ __forceinline__ bool iou_gt_half(float inter, float uni) {
    double b = (double)fmaxf(uni, 1e-8f);
    return (double)inter * 2.0 > b * 0x1.000001p0;
}
__device__ __forceinline__ float parse_imgf(int raw) {
    return (raw > 0 && raw < 1000000) ? (float)raw : __int_as_float(raw);
}

// ---------------- kernel 1: decode on the full chip ----------------
__global__ __launch_bounds__(256)
void decode_kernel(const float* __restrict__ class_logit,
                   const float* __restrict__ box_reg,
                   const float* __restrict__ proposal,
                   const int* __restrict__ image_shape_p,
                   unsigned long long* __restrict__ wskey,   // [2][NUNITS]
                   float2* __restrict__ wbox)                // [2][NUNITS]
{
#pragma clang fp contract(off)
    const int t = blockIdx.x * 256 + threadIdx.x;   // 0..NUNITS-1
    const int n = t & (N_PROP - 1);
    const float imgf = parse_imgf(image_shape_p[0]);

    const float* lg = class_logit + (size_t)t * C_CLS;
    float l0 = lg[0], l1 = lg[1], l2 = lg[2];
    float mx = fmaxf(l0, fmaxf(l1, l2));
    float e0 = (float)exp((double)(l0 - mx));
    float e1 = (float)exp((double)(l1 - mx));
    float e2 = (float)exp((double)(l2 - mx));
    float denom = (e0 + e1) + e2;

    const float* pp = proposal + (size_t)t * 2;
    float pA = pp[0], pB = pp[1];
    float w = pB - pA;
    float ctr = pA + 0.5f * w;

    const float* dr = box_reg + (size_t)t * (2 * C_CLS);
    float d1x = dr[2], d1w = dr[3], d2x = dr[4], d2w = dr[5];

#pragma unroll
    for (int c = 0; c < 2; ++c) {
        float score = ((c == 0) ? e1 : e2) / denom;
        float dx = (c == 0) ? d1x : d2x;                 // / WX == 1
        float dw = fminf((c == 0) ? d1w : d2w, 4.0f);    // / WW == 1, clamp 4
        float tt = dx * w;
        float pc = tt + ctr;
        float pw = (float)exp((double)dw) * w;
        float half = 0.5f * pw;
        float lo = pc - half;
        float hi = pc + half;
        lo = fminf(fmaxf(lo, 0.0f), imgf);
        hi = fminf(fmaxf(hi, 0.0f), imgf);
        bool valid = ((hi - lo) >= 10.0f) && (score >= 0.05f);
        float ms = valid ? score : -1e9f;
        unsigned int u = __float_as_uint(ms);
        unsigned int e = (u & 0x80000000u) ? ~u : (u | 0x80000000u);  // order-preserving
        wskey[c * NUNITS + t] = ((unsigned long long)e << 32) |
                                (unsigned long long)(0xFFFFFFFFu - (unsigned int)n);
        wbox[c * NUNITS + t] = make_float2(lo, hi);
    }
}

// ---------------- kernel 2: sort + NMS + top-K per (img,cls) ----------------
__global__ __launch_bounds__(NTHREADS)
void roiheads_kernel(const unsigned long long* __restrict__ wskey,
                     const float2* __restrict__ wbox,
                     float* __restrict__ out)
{
#pragma clang fp contract(off)
    __shared__ unsigned long long skey[N_PROP];     // 16 KB sort keys
    __shared__ float slo[N_PROP], shi[N_PROP];      // boxes in sorted order
    __shared__ unsigned char keep[N_PROP];
    __shared__ unsigned short alv[2][N_PROP];       // alive (undecided) sorted positions
    __shared__ float clo[64], chi[64];              // current chunk's kept boxes
    __shared__ unsigned long long sup[64];          // chunk suppression matrix rows
    __shared__ unsigned long long kmask[NBLK64];
    __shared__ int wsum[NWAVES];
    __shared__ int sh_nvalid;

    const int tid = threadIdx.x;
    const int lane = tid & 63;
    const int wid = tid >> 6;
    const int img = blockIdx.x >> 1;
    const int cls = blockIdx.x & 1;
    const size_t base = (size_t)cls * NUNITS + (size_t)img * N_PROP;

    if (tid == 0) sh_nvalid = 0;

    // register-bitonic mapping: thread holds sorted-net positions p0 = 2*tid
    // arranged so wave w owns the contiguous 128-item span [128w, 128w+128).
    const int p0 = (wid << 7) | (lane << 1);
    const int p1 = p0 | 1;

    unsigned long long r0 = wskey[base + p0];
    unsigned long long r1 = wskey[base + p1];

    // ---- bitonic sort, descending; j<=64 in registers via shfl_xor ----
    auto pass_inreg = [&](int k, int j) {
        if (j == 1) {
            bool desc = ((p0 & k) == 0);
            bool sw = desc ? (r0 < r1) : (r0 > r1);
            if (sw) { unsigned long long t = r0; r0 = r1; r1 = t; }
        } else {
            int lx = j >> 1;
            unsigned long long o0 = shfl_xor_u64(r0, lx);
            unsigned long long o1 = shfl_xor_u64(r1, lx);
            bool desc = ((p0 & k) == 0);     // same for p0/p1 (k>=4 here)
            bool lower = ((p0 & j) == 0);    // same for p0/p1 (j>=2 here)
            bool takeMax = (lower == desc);
            r0 = takeMax ? (r0 > o0 ? r0 : o0) : (r0 < o0 ? r0 : o0);
            r1 = takeMax ? (r1 > o1 ? r1 : o1) : (r1 < o1 ? r1 : o1);
        }
    };

    for (int k = 2; k <= 128; k <<= 1)
        for (int j = k >> 1; j >= 1; j >>= 1)
            pass_inreg(k, j);

    for (int k = 256; k <= N_PROP; k <<= 1) {
        skey[p0] = r0; skey[p1] = r1;
        __syncthreads();
        for (int j = k >> 1; j >= 128; j >>= 1) {
            int i = ((tid & ~(j - 1)) << 1) | (tid & (j - 1));
            int part = i | j;
            unsigned long long a = skey[i], b = skey[part];
            bool desc_blk = ((i & k) == 0);
            bool sw = desc_blk ? (a < b) : (a > b);
            if (sw) { skey[i] = b; skey[part] = a; }
            __syncthreads();
        }
        r0 = skey[p0]; r1 = skey[p1];
        for (int j = 64; j >= 1; j >>= 1)
            pass_inreg(k, j);
    }
    skey[p0] = r0; skey[p1] = r1;
    __syncthreads();

    // ---- gather sorted boxes (from ws via L2), count valid, init alive list ----
    for (int i = tid; i < N_PROP; i += NTHREADS) {
        unsigned long long kk = skey[i];
        unsigned int e = (unsigned int)(kk >> 32);
        unsigned int sb = (e & 0x80000000u) ? (e & 0x7FFFFFFFu) : ~e;
        float s = __uint_as_float(sb);
        unsigned int n = 0xFFFFFFFFu - (unsigned int)(kk & 0xFFFFFFFFull);
        float2 bx = wbox[base + n];
        slo[i] = bx.x;
        shi[i] = bx.y;
        keep[i] = 0;
        bool v = (s > -5e8f);    // keep0 = s > 0.5*NEG  (valid items sort first)
        unsigned long long mb = __ballot(v);
        if (lane == 0) atomicAdd(&sh_nvalid, __popcll(mb));
        alv[0][i] = (unsigned short)i;
    }
    __syncthreads();

    int na = sh_nvalid;
    int cur = 0;
    int tk = 0;
    const unsigned long long below = (1ull << lane) - 1ull;

    // ---- greedy NMS: parallel 64x64 suppression matrix + scalar mask resolve ----
    while (na > 0) {
        const int m = (na < 64) ? na : 64;

        // (a) this wave's column boxes (chunk items 0..63), loaded once per round
        unsigned short cp = alv[cur][lane];
        bool cin = (lane < m);
        float qloc = cin ? slo[cp] : 0.0f;
        float qhic = cin ? shi[cp] : 0.0f;

        // (b) build suppression rows: 4 rows per wave, all 16 waves in parallel
#pragma unroll
        for (int rr4 = 0; rr4 < 4; ++rr4) {
            int rr = (wid << 2) | rr4;
            unsigned long long row = 0;
            if (rr < m) {
                unsigned short rp = alv[cur][rr];     // wave-uniform
                float rlo = slo[rp], rhi = shi[rp];   // broadcast LDS reads
                float inter = fmaxf(fminf(rhi, qhic) - fmaxf(rlo, qloc), 0.0f);
                float uni = (rhi - rlo) + (qhic - qloc) - inter;  // w_r + w_c (commutative)
                bool kill = cin && (lane > rr) && iou_gt_half(inter, uni);
                row = __ballot(kill);
            }
            if (lane == 0) sup[rr] = row;
        }
        __syncthreads();

        // (c) scalar greedy mask recurrence (redundant per wave; rows lane-distributed)
        unsigned long long rw = sup[lane];
        unsigned long long A = (m >= 64) ? ~0ull : ((1ull << m) - 1ull);
        unsigned long long kept = 0;
        while (A) {
            int c = __builtin_ctzll(A);
            kept |= (1ull << c);
            A &= ~(readlane_u64(rw, c) | (1ull << c));
        }
        const int cnt = __popcll(kept);

        // (d) wave 0 marks keep + builds compact kept-box list
        if (wid == 0) {
            bool alive = cin && ((kept >> lane) & 1ull);
            if (alive) {
                keep[cp] = 1;
                int rank = __popcll(kept & below);
                clo[rank] = qloc; chi[rank] = qhic;
            }
        }
        __syncthreads();
        tk += cnt;
        if (tk >= K_OUT) break;   // provably unused decisions (never fires if nk<K)

        // (e) sweep remaining alive items vs kept boxes (registers + readlane)
        float klo = 0.0f, khi = 0.0f;
        if (lane < cnt) { klo = clo[lane]; khi = chi[lane]; }
        int base2 = 0;
        for (int start = 64; start < na; start += NTHREADS) {
            int t2 = start + tid;
            unsigned short q = 0;
            bool surv = false;
            if (t2 < na) {
                q = alv[cur][t2];
                float qlo = slo[q], qhi = shi[q];
                float qw = qhi - qlo;
                bool dead = false;
                for (int r = 0; r < cnt; ++r) {
                    float cl = readlane_f(klo, r);
                    float ch = readlane_f(khi, r);
                    float inter = fmaxf(fminf(qhi, ch) - fmaxf(qlo, cl), 0.0f);
                    float uni = qw + (ch - cl) - inter;
                    dead |= iou_gt_half(inter, uni);
                }
                surv = !dead;
            }
            unsigned long long mb = __ballot(surv);
            if (lane == 0) wsum[wid] = __popcll(mb);
            __syncthreads();
            int off = base2, tot = base2;
            for (int w2 = 0; w2 < NWAVES; ++w2) {
                int c2 = wsum[w2];
                if (w2 < wid) off += c2;
                tot += c2;
            }
            if (surv) alv[cur ^ 1][off + __popcll(mb & below)] = q;
            base2 = tot;
            __syncthreads();
        }
        na = base2;
        cur ^= 1;
    }

    // ---- top-K fill (reproduces lax.top_k tie-breaking exactly) ----
    for (int blk = wid; blk < NBLK64; blk += NWAVES) {
        bool kk = keep[blk * 64 + lane] != 0;
        unsigned long long mb = __ballot(kk);
        if (lane == 0) kmask[blk] = mb;
    }
    __syncthreads();
    {
        float* outp = out + (((size_t)img * 2 + cls) * K_OUT) * 3;
        for (int blk = wid; blk < NBLK64; blk += NWAVES) {
            int kc = 0, nc = 0, nk = 0;
            for (int b = 0; b < NBLK64; ++b) {
                int pc = __popcll(kmask[b]);
                nk += pc;
                if (b < blk) { kc += pc; nc += 64 - pc; }
            }
            if (kc >= K_OUT && nk + nc >= K_OUT && nc >= K_OUT) continue;
            int p = blk * 64 + lane;
            unsigned long long mb = kmask[blk];
            bool k = (mb >> lane) & 1ull;
            int rk = kc + __popcll(mb & below);
            int rn = nc + __popcll((~mb) & below);
            if (k) {
                if (rk < K_OUT) {
                    unsigned long long kk2 = skey[p];
                    unsigned int e = (unsigned int)(kk2 >> 32);
                    unsigned int sb = (e & 0x80000000u) ? (e & 0x7FFFFFFFu) : ~e;
                    outp[rk * 3 + 0] = slo[p];
                    outp[rk * 3 + 1] = shi[p];
                    outp[rk * 3 + 2] = __uint_as_float(sb);
                }
            } else {
                int oi = nk + rn;
                if (oi < K_OUT) {
                    outp[oi * 3 + 0] = slo[p];
                    outp[oi * 3 + 1] = shi[p];
                    outp[oi * 3 + 2] = -1e9f;
                }
            }
        }
    }
}

extern "C" void kernel_launch(void* const* d_in, const int* in_sizes, int n_in,
                              void* d_out, int out_size, void* d_ws, size_t ws_size,
                              hipStream_t stream) {
    const float* class_logit = (const float*)d_in[0];
    const float* box_reg     = (const float*)d_in[1];
    const float* prop        = (const float*)d_in[2];
    const int*   image_shape = (const int*)d_in[3];
    float* out = (float*)d_out;

    unsigned long long* wskey = (unsigned long long*)d_ws;            // 512 KB
    float2* wbox = (float2*)((char*)d_ws + 2 * NUNITS * sizeof(unsigned long long));

    decode_kernel<<<dim3(NUNITS / 256), dim3(256), 0, stream>>>(
        class_logit, box_reg, prop, image_shape, wskey, wbox);
    roiheads_kernel<<<dim3(B_IMG * 2), dim3(NTHREADS), 0, stream>>>(
        wskey, wbox, out);
}

// Round 10
// 95.123 us; speedup vs baseline: 1.6748x; 1.0296x over previous
//
#include <hip/hip_runtime.h>
#include <math.h>

#define B_IMG 16
#define N_PROP 2048
#define C_CLS 3
#define K_OUT 100
#define NTHREADS 1024
#define NWAVES (NTHREADS / 64)
#define NBLK64 (N_PROP / 64)
#define NUNITS (B_IMG * N_PROP)           // 32768 (img,n) units
#define NTHA 256                          // presort kernel threads
#define RUN 512                           // presorted run length

__device__ __forceinline__ unsigned long long shfl_xor_u64(unsigned long long v, int lx) {
    unsigned int lo = (unsigned int)__shfl_xor((int)(unsigned int)(v & 0xffffffffull), lx, 64);
    unsigned int hi = (unsigned int)__shfl_xor((int)(unsigned int)(v >> 32), lx, 64);
    return ((unsigned long long)hi << 32) | (unsigned long long)lo;
}
__device__ __forceinline__ float readlane_f(float v, int l) {
    return __int_as_float(__builtin_amdgcn_readlane(__float_as_int(v), l));
}
__device__ __forceinline__ unsigned long long readlane_u64(unsigned long long v, int l) {
    unsigned int lo = (unsigned int)__builtin_amdgcn_readlane((int)(unsigned int)(v & 0xffffffffull), l);
    unsigned int hi = (unsigned int)__builtin_amdgcn_readlane((int)(unsigned int)(v >> 32), l);
    return ((unsigned long long)hi << 32) | (unsigned long long)lo;
}
// Exact replacement for: RN(inter / max(uni,1e-8f)) > 0.5f
// RN(a/b) > 0.5 <=> a/b > 0.5+2^-25 <=> 2a > b*(1+2^-24); b*(1+2^-24) exact in
// double (24+25=49 < 53 bits). Bit-equivalent to the reference decision.
__device__ __forceinline__ bool iou_gt_half(float inter, float uni) {
    double b = (double)fmaxf(uni, 1e-8f);
    return (double)inter * 2.0 > b * 0x1.000001p0;
}
__device__ __forceinline__ float parse_imgf(int raw) {
    return (raw > 0 && raw < 1000000) ? (float)raw : __int_as_float(raw);
}

// ---------------- kernel A: fused decode + 512-run presort ----------------
// 128 blocks: one per (img,cls,quarter). Sorts its run descending iff
// (run_start & 512)==0 (mirrored bitonic network via `flip`), which is
// exactly the state of the standard full network after stage k=512.
__global__ __launch_bounds__(NTHA)
void decode_sort_kernel(const float* __restrict__ class_logit,
                        const float* __restrict__ box_reg,
                        const float* __restrict__ proposal,
                        const int* __restrict__ image_shape_p,
                        unsigned long long* __restrict__ wskey,   // [2][NUNITS]
                        float2* __restrict__ wbox)                // [2][NUNITS]
{
#pragma clang fp contract(off)
    __shared__ unsigned long long skey[RUN];

    const int tid = threadIdx.x;
    const int lane = tid & 63;
    const int wid = tid >> 6;
    const int u = blockIdx.x >> 2;
    const int q = blockIdx.x & 3;
    const int img = u >> 1;
    const int cls = u & 1;                       // fg class index-1
    const bool flip = (q & 1) != 0;              // odd quarters sort ascending
    const int off = q * RUN;
    const size_t base = (size_t)cls * NUNITS + (size_t)img * N_PROP;
    const float imgf = parse_imgf(image_shape_p[0]);

    // decode 512 proposals for this class (identical fp sequence to reference)
    for (int i = tid; i < RUN; i += NTHA) {
        const int n = off + i;
        const size_t g = (size_t)img * N_PROP + n;
        const float* lg = class_logit + g * C_CLS;
        float l0 = lg[0], l1 = lg[1], l2 = lg[2];
        float mx = fmaxf(l0, fmaxf(l1, l2));
        float e0 = (float)exp((double)(l0 - mx));
        float e1 = (float)exp((double)(l1 - mx));
        float e2 = (float)exp((double)(l2 - mx));
        float denom = (e0 + e1) + e2;
        float score = ((cls == 0) ? e1 : e2) / denom;

        const float* dr = box_reg + g * (2 * C_CLS) + 2 * (cls + 1);
        float dx = dr[0];                       // / WX == 1
        float dw = fminf(dr[1], 4.0f);          // / WW == 1, clamp 4
        const float* pp = proposal + g * 2;
        float pA = pp[0], pB = pp[1];
        float w = pB - pA;
        float ctr = pA + 0.5f * w;
        float tt = dx * w;
        float pc = tt + ctr;
        float pw = (float)exp((double)dw) * w;
        float half = 0.5f * pw;
        float lo = pc - half;
        float hi = pc + half;
        lo = fminf(fmaxf(lo, 0.0f), imgf);
        hi = fminf(fmaxf(hi, 0.0f), imgf);
        bool valid = ((hi - lo) >= 10.0f) && (score >= 0.05f);
        float ms = valid ? score : -1e9f;
        wbox[base + n] = make_float2(lo, hi);
        unsigned int uu = __float_as_uint(ms);
        unsigned int e = (uu & 0x80000000u) ? ~uu : (uu | 0x80000000u); // order-preserving
        skey[i] = ((unsigned long long)e << 32) |
                  (unsigned long long)(0xFFFFFFFFu - (unsigned int)n);  // idx asc on ties
    }
    __syncthreads();

    // hybrid reg/LDS bitonic over the 512-run (direction mirrored by flip)
    const int p0 = (wid << 7) | (lane << 1);    // == 2*tid, wave-contiguous spans
    const int p1 = p0 | 1;
    unsigned long long r0 = skey[p0], r1 = skey[p1];

    auto pass_inreg = [&](int k, int j) {
        bool desc = (((p0 & k) == 0) != flip);
        if (j == 1) {
            bool sw = desc ? (r0 < r1) : (r0 > r1);
            if (sw) { unsigned long long t = r0; r0 = r1; r1 = t; }
        } else {
            int lx = j >> 1;
            unsigned long long o0 = shfl_xor_u64(r0, lx);
            unsigned long long o1 = shfl_xor_u64(r1, lx);
            bool lower = ((p0 & j) == 0);
            bool takeMax = (lower == desc);
            r0 = takeMax ? (r0 > o0 ? r0 : o0) : (r0 < o0 ? r0 : o0);
            r1 = takeMax ? (r1 > o1 ? r1 : o1) : (r1 < o1 ? r1 : o1);
        }
    };

    for (int k = 2; k <= 128; k <<= 1)
        for (int j = k >> 1; j >= 1; j >>= 1)
            pass_inreg(k, j);

    for (int k = 256; k <= RUN; k <<= 1) {
        skey[p0] = r0; skey[p1] = r1;
        __syncthreads();
        for (int j = k >> 1; j >= 128; j >>= 1) {
            int i = ((tid & ~(j - 1)) << 1) | (tid & (j - 1));
            int part = i | j;
            unsigned long long a = skey[i], b = skey[part];
            bool desc_blk = (((i & k) == 0) != flip);
            bool sw = desc_blk ? (a < b) : (a > b);
            if (sw) { skey[i] = b; skey[part] = a; }
            __syncthreads();
        }
        r0 = skey[p0]; r1 = skey[p1];
        for (int j = 64; j >= 1; j >>= 1)
            pass_inreg(k, j);
    }
    wskey[base + off + p0] = r0;
    wskey[base + off + p1] = r1;
}

// ---------------- kernel B: bitonic merge (k=1024,2048) + NMS + top-K ----------------
__global__ __launch_bounds__(NTHREADS)
void roiheads_kernel(const unsigned long long* __restrict__ wskey,
                     const float2* __restrict__ wbox,
                     float* __restrict__ out)
{
#pragma clang fp contract(off)
    __shared__ unsigned long long skey[N_PROP];     // 16 KB sort keys
    __shared__ float slo[N_PROP], shi[N_PROP];      // boxes in sorted order
    __shared__ unsigned char keep[N_PROP];
    __shared__ unsigned short alv[2][N_PROP];       // alive (undecided) sorted positions
    __shared__ float clo[64], chi[64];              // current chunk's kept boxes
    __shared__ unsigned long long sup[64];          // chunk suppression matrix rows
    __shared__ unsigned long long kmask[NBLK64];
    __shared__ int wsum[NWAVES];
    __shared__ int sh_nvalid;

    const int tid = threadIdx.x;
    const int lane = tid & 63;
    const int wid = tid >> 6;
    const int img = blockIdx.x >> 1;
    const int cls = blockIdx.x & 1;
    const size_t base = (size_t)cls * NUNITS + (size_t)img * N_PROP;

    if (tid == 0) sh_nvalid = 0;

    const int p0 = (wid << 7) | (lane << 1);   // == 2*tid
    const int p1 = p0 | 1;

    unsigned long long r0 = wskey[base + p0];  // coalesced 16B/thread
    unsigned long long r1 = wskey[base + p1];

    auto pass_inreg = [&](int k, int j) {
        if (j == 1) {
            bool desc = ((p0 & k) == 0);
            bool sw = desc ? (r0 < r1) : (r0 > r1);
            if (sw) { unsigned long long t = r0; r0 = r1; r1 = t; }
        } else {
            int lx = j >> 1;
            unsigned long long o0 = shfl_xor_u64(r0, lx);
            unsigned long long o1 = shfl_xor_u64(r1, lx);
            bool desc = ((p0 & k) == 0);
            bool lower = ((p0 & j) == 0);
            bool takeMax = (lower == desc);
            r0 = takeMax ? (r0 > o0 ? r0 : o0) : (r0 < o0 ? r0 : o0);
            r1 = takeMax ? (r1 > o1 ? r1 : o1) : (r1 < o1 ? r1 : o1);
        }
    };

    // only the merge stages remain: runs of 512 arrive presorted in
    // alternating directions (network state after stage k=512).
    for (int k = 1024; k <= N_PROP; k <<= 1) {
        skey[p0] = r0; skey[p1] = r1;
        __syncthreads();
        for (int j = k >> 1; j >= 128; j >>= 1) {
            int i = ((tid & ~(j - 1)) << 1) | (tid & (j - 1));
            int part = i | j;
            unsigned long long a = skey[i], b = skey[part];
            bool desc_blk = ((i & k) == 0);
            bool sw = desc_blk ? (a < b) : (a > b);
            if (sw) { skey[i] = b; skey[part] = a; }
            __syncthreads();
        }
        r0 = skey[p0]; r1 = skey[p1];
        for (int j = 64; j >= 1; j >>= 1)
            pass_inreg(k, j);
    }
    skey[p0] = r0; skey[p1] = r1;
    __syncthreads();

    // ---- gather sorted boxes (from ws via L2), count valid, init alive list ----
    for (int i = tid; i < N_PROP; i += NTHREADS) {
        unsigned long long kk = skey[i];
        unsigned int e = (unsigned int)(kk >> 32);
        unsigned int sb = (e & 0x80000000u) ? (e & 0x7FFFFFFFu) : ~e;
        float s = __uint_as_float(sb);
        unsigned int n = 0xFFFFFFFFu - (unsigned int)(kk & 0xFFFFFFFFull);
        float2 bx = wbox[base + n];
        slo[i] = bx.x;
        shi[i] = bx.y;
        keep[i] = 0;
        bool v = (s > -5e8f);    // keep0 = s > 0.5*NEG  (valid items sort first)
        unsigned long long mb = __ballot(v);
        if (lane == 0) atomicAdd(&sh_nvalid, __popcll(mb));
        alv[0][i] = (unsigned short)i;
    }
    __syncthreads();

    int na = sh_nvalid;
    int cur = 0;
    int tk = 0;
    const unsigned long long below = (1ull << lane) - 1ull;

    // ---- greedy NMS: parallel 64x64 suppression matrix + scalar mask resolve ----
    while (na > 0) {
        const int m = (na < 64) ? na : 64;

        unsigned short cp = alv[cur][lane];
        bool cin = (lane < m);
        float qloc = cin ? slo[cp] : 0.0f;
        float qhic = cin ? shi[cp] : 0.0f;

#pragma unroll
        for (int rr4 = 0; rr4 < 4; ++rr4) {
            int rr = (wid << 2) | rr4;
            unsigned long long row = 0;
            if (rr < m) {
                unsigned short rp = alv[cur][rr];     // wave-uniform
                float rlo = slo[rp], rhi = shi[rp];   // broadcast LDS reads
                float inter = fmaxf(fminf(rhi, qhic) - fmaxf(rlo, qloc), 0.0f);
                float uni = (rhi - rlo) + (qhic - qloc) - inter;
                bool kill = cin && (lane > rr) && iou_gt_half(inter, uni);
                row = __ballot(kill);
            }
            if (lane == 0) sup[rr] = row;
        }
        __syncthreads();

        unsigned long long rw = sup[lane];
        unsigned long long A = (m >= 64) ? ~0ull : ((1ull << m) - 1ull);
        unsigned long long kept = 0;
        while (A) {
            int c = __builtin_ctzll(A);
            kept |= (1ull << c);
            A &= ~(readlane_u64(rw, c) | (1ull << c));
        }
        const int cnt = __popcll(kept);

        if (wid == 0) {
            bool alive = cin && ((kept >> lane) & 1ull);
            if (alive) {
                keep[cp] = 1;
                int rank = __popcll(kept & below);
                clo[rank] = qloc; chi[rank] = qhic;
            }
        }
        __syncthreads();
        tk += cnt;
        if (tk >= K_OUT) break;   // later decisions provably unused

        float klo = 0.0f, khi = 0.0f;
        if (lane < cnt) { klo = clo[lane]; khi = chi[lane]; }
        int base2 = 0;
        for (int start = 64; start < na; start += NTHREADS) {
            int t2 = start + tid;
            unsigned short qq = 0;
            bool surv = false;
            if (t2 < na) {
                qq = alv[cur][t2];
                float qlo = slo[qq], qhi = shi[qq];
                float qw = qhi - qlo;
                bool dead = false;
                for (int r = 0; r < cnt; ++r) {
                    float cl = readlane_f(klo, r);
                    float ch = readlane_f(khi, r);
                    float inter = fmaxf(fminf(qhi, ch) - fmaxf(qlo, cl), 0.0f);
                    float uni = qw + (ch - cl) - inter;
                    dead |= iou_gt_half(inter, uni);
                }
                surv = !dead;
            }
            unsigned long long mb = __ballot(surv);
            if (lane == 0) wsum[wid] = __popcll(mb);
            __syncthreads();
            int off2 = base2, tot = base2;
            for (int w2 = 0; w2 < NWAVES; ++w2) {
                int c2 = wsum[w2];
                if (w2 < wid) off2 += c2;
                tot += c2;
            }
            if (surv) alv[cur ^ 1][off2 + __popcll(mb & below)] = qq;
            base2 = tot;
            __syncthreads();
        }
        na = base2;
        cur ^= 1;
    }

    // ---- top-K fill (reproduces lax.top_k tie-breaking exactly) ----
    for (int blk = wid; blk < NBLK64; blk += NWAVES) {
        bool kk = keep[blk * 64 + lane] != 0;
        unsigned long long mb = __ballot(kk);
        if (lane == 0) kmask[blk] = mb;
    }
    __syncthreads();
    {
        float* outp = out + (((size_t)img * 2 + cls) * K_OUT) * 3;
        for (int blk = wid; blk < NBLK64; blk += NWAVES) {
            int kc = 0, nc = 0, nk = 0;
            for (int b = 0; b < NBLK64; ++b) {
                int pc = __popcll(kmask[b]);
                nk += pc;
                if (b < blk) { kc += pc; nc += 64 - pc; }
            }
            if (kc >= K_OUT && nk + nc >= K_OUT && nc >= K_OUT) continue;
            int p = blk * 64 + lane;
            unsigned long long mb = kmask[blk];
            bool k = (mb >> lane) & 1ull;
            int rk = kc + __popcll(mb & below);
            int rn = nc + __popcll((~mb) & below);
            if (k) {
                if (rk < K_OUT) {
                    unsigned long long kk2 = skey[p];
                    unsigned int e = (unsigned int)(kk2 >> 32);
                    unsigned int sb = (e & 0x80000000u) ? (e & 0x7FFFFFFFu) : ~e;
                    outp[rk * 3 + 0] = slo[p];
                    outp[rk * 3 + 1] = shi[p];
                    outp[rk * 3 + 2] = __uint_as_float(sb);
                }
            } else {
                int oi = nk + rn;
                if (oi < K_OUT) {
                    outp[oi * 3 + 0] = slo[p];
                    outp[oi * 3 + 1] = shi[p];
                    outp[oi * 3 + 2] = -1e9f;
                }
            }
        }
    }
}

extern "C" void kernel_launch(void* const* d_in, const int* in_sizes, int n_in,
                              void* d_out, int out_size, void* d_ws, size_t ws_size,
                              hipStream_t stream) {
    const float* class_logit = (const float*)d_in[0];
    const float* box_reg     = (const float*)d_in[1];
    const float* prop        = (const float*)d_in[2];
    const int*   image_shape = (const int*)d_in[3];
    float* out = (float*)d_out;

    unsigned long long* wskey = (unsigned long long*)d_ws;            // 512 KB
    float2* wbox = (float2*)((char*)d_ws + 2 * NUNITS * sizeof(unsigned long long));

    decode_sort_kernel<<<dim3(B_IMG * 2 * 4), dim3(NTHA), 0, stream>>>(
        class_logit, box_reg, prop, image_shape, wskey, wbox);
    roiheads_kernel<<<dim3(B_IMG * 2), dim3(NTHREADS), 0, stream>>>(
        wskey, wbox, out);
}